// Round 1
// baseline (160.140 us; speedup 1.0000x reference)
//
#include <hip/hip_runtime.h>

// QuantizationLayer: num = rint(x * 2^B - 0.5) (round-half-even, matches
// jnp.round); num %= 256; emit B bits MSB-first as floats.
//
// v2: memory-bound shape is 33.5 MB read + 134 MB write = 167.8 MB
// -> ~25 us floor at the ~6.8 TB/s pure-write ceiling the harness's own
// fillBuffer kernel demonstrates. Changes vs v1:
//  - 8 elements/thread, all 8 loads issued before any use (8 HBM misses in
//    flight per thread instead of 1 -> latency-bound fix)
//  - 4096 workgroups instead of 32768 (each WG now moves 40 KB not 5 KB)
//  - non-temporal load/store: output is write-once streaming (134 MB),
//    input read-once; don't burn L2/L3 retention on either.
//  - every load instruction stays 256 B wave-coalesced, every store stays
//    1024 B wave-coalesced (same as v1 -- this was already right).

typedef float f32x4 __attribute__((ext_vector_type(4)));

constexpr int BLOCK = 256;
constexpr int UNROLL = 8;  // elements per thread

__device__ __forceinline__ f32x4 bits_of(float v, float step) {
    // rintf -> v_rndne_f32 (round half to even), matches jnp.round exactly
    int num = (int)rintf(v * step - 0.5f);
    num &= 255;  // uint8 wraparound (num % 256)
    f32x4 o;
    o.x = (float)((num >> 3) & 1);
    o.y = (float)((num >> 2) & 1);
    o.z = (float)((num >> 1) & 1);
    o.w = (float)( num       & 1);
    return o;
}

__global__ __launch_bounds__(BLOCK) void quant_bits_b4_v2(
        const float* __restrict__ x, f32x4* __restrict__ out4, int n) {
    int base = blockIdx.x * (BLOCK * UNROLL) + threadIdx.x;

    if ((blockIdx.x + 1) * (BLOCK * UNROLL) <= n) {
        // full tile: no bounds checks, 8 loads in flight, then 8 stores
        float v[UNROLL];
#pragma unroll
        for (int k = 0; k < UNROLL; ++k)
            v[k] = __builtin_nontemporal_load(x + base + k * BLOCK);
#pragma unroll
        for (int k = 0; k < UNROLL; ++k)
            __builtin_nontemporal_store(bits_of(v[k], 16.0f),
                                        out4 + base + k * BLOCK);
    } else {
        // tail tile (not taken for 4096x2048, kept for generality)
        for (int k = 0; k < UNROLL; ++k) {
            int i = base + k * BLOCK;
            if (i < n) out4[i] = bits_of(x[i], 16.0f);
        }
    }
}

__global__ void quant_bits_generic(const float* __restrict__ x,
                                   float* __restrict__ out, int n,
                                   int B, float step) {
    int i = blockIdx.x * blockDim.x + threadIdx.x;
    if (i >= n) return;
    float v = x[i];
    int num = (int)rintf(v * step - 0.5f);
    num &= 255;
    float* o = out + (size_t)i * (size_t)B;
    for (int j = 0; j < B; ++j) {
        o[j] = (float)((num >> (B - 1 - j)) & 1);
    }
}

extern "C" void kernel_launch(void* const* d_in, const int* in_sizes, int n_in,
                              void* d_out, int out_size, void* d_ws, size_t ws_size,
                              hipStream_t stream) {
    const float* x = (const float*)d_in[0];
    float* out = (float*)d_out;
    int n = in_sizes[0];                 // 4096*2048 = 8388608 input elements
    int B = out_size / n;                // recover B on host: out_size = n*B

    if (B == 4) {
        const int tile = BLOCK * UNROLL;             // 2048 elements / block
        int grid = (n + tile - 1) / tile;            // 4096 blocks
        quant_bits_b4_v2<<<grid, BLOCK, 0, stream>>>(
            x, reinterpret_cast<f32x4*>(out), n);
    } else {
        const int block = 256;
        int grid = (n + block - 1) / block;
        float step = (float)(1u << B);
        quant_bits_generic<<<grid, block, 0, stream>>>(x, out, n, B, step);
    }
}